// Round 5
// baseline (1127.870 us; speedup 1.0000x reference)
//
#include <hip/hip_runtime.h>
#include <hip/hip_bf16.h>
#include <math.h>

#define Bn   256
#define Tn   128
#define HID  64
#define MCn  30

typedef __attribute__((ext_vector_type(8))) short bf16x8;
typedef __attribute__((ext_vector_type(4))) float f32x4;

// ---------------------------------------------------------------------------
__device__ __forceinline__ float rcp_(float x) { return __builtin_amdgcn_rcpf(x); }
__device__ __forceinline__ float tanhf_(float x) {
    float xx = fminf(fmaxf(x, -9.0f), 9.0f);
    float e  = __expf(2.0f * xx);
    return (e - 1.0f) * rcp_(e + 1.0f);
}
__device__ __forceinline__ float sigmoidf_(float x) {
    return rcp_(1.0f + __expf(-x));
}
__device__ __forceinline__ float softplusf_(float z) {
    float e = __expf(-fabsf(z));
    return fmaxf(z, 0.0f) + __logf(1.0f + e);
}
__device__ __forceinline__ unsigned short f2b(float f) {
    union { float f; unsigned u; } v; v.f = f;
    unsigned r = v.u + 0x7FFF + ((v.u >> 16) & 1);
    return (unsigned short)(r >> 16);
}
// pack 2 fp32 -> bf16x2 (v_cvt_pk_bf16_f32 on gfx950), lo = a, hi = b
__device__ __forceinline__ unsigned pk2(float a, float b) {
    union { __hip_bfloat162 h2; unsigned u; } cv;
    cv.h2 = __float22bfloat162_rn(make_float2(a, b));
    return cv.u;
}

// parv (fp32, 768 floats):
//   [0] b0[l*64+m]  [128] w0t[l*64+m]  [256] b1[l*64+m]
//   [384] b2c[l*64+i]=fb2[l][act+(i&31)+64*(i>>5)]
//   [512] ftwa[l*32+i]=ftw[l][act+i]  [576] ftwb[l*32+i]=ftw[l][64+act+i]
//   [640] Wi[64]  [704] pad
// parwb (bf16, 23552 ushorts, A-operand [out m][in k]):
//   [0]     w0a[l][64][40]: fW0[l][32l+k][m], k<32
//   [5120]  w1b[l][64][72]: fW1[l][k][m],     k<64
//   [14336] w2b[l][64][72]: fW2[l][k][act+(m&31)+64*(m>>5)], k<64
extern "C" __global__ __launch_bounds__(256)
void prep_kernel(const int* __restrict__ marks, const float* __restrict__ mask,
                 const float* __restrict__ emb, const float* __restrict__ fW0,
                 const float* __restrict__ fW1, const float* __restrict__ fW2,
                 const float* __restrict__ fb0, const float* __restrict__ fb1,
                 const float* __restrict__ fb2, const float* __restrict__ ftw,
                 const float* __restrict__ Wi, const float* __restrict__ W_ih,
                 const float* __restrict__ b_ih, const float* __restrict__ b_hh,
                 float* __restrict__ gc, float* __restrict__ invd,
                 float* __restrict__ seqw2, float* __restrict__ parv,
                 unsigned short* __restrict__ parwb)
{
    __shared__ float red[4];
    const int blk = blockIdx.x, tid = threadIdx.x;
    if (blk < Bn) {
        const int mark = marks[blk * Tn + 1];
        const float* er = emb + mark * HID;
        const float* wr = W_ih + tid * 65 + 1;
        float acc = b_ih[tid] + b_hh[tid];
        #pragma unroll
        for (int k = 0; k < HID; k++) acc += er[k] * wr[k];
        gc[blk * 256 + tid] = acc;
    } else if (blk == Bn) {
        float s = 0.f;
        for (int i = tid; i < Bn * Tn; i += 256) s += mask[i];
        #pragma unroll
        for (int off = 32; off >= 1; off >>= 1) s += __shfl_xor(s, off, 64);
        if ((tid & 63) == 0) red[tid >> 6] = s;
        __syncthreads();
        if (tid == 0) invd[0] = 1.0f / (red[0] + red[1] + red[2] + red[3]);
    } else if (blk == Bn + 1) {
        for (int i = tid; i < 8192; i += 256) {
            int col = i & 63, k = (i >> 6) & 63, l = i >> 12;
            int act = 32 * (1 - l);
            seqw2[i] = fW2[(l * 64 + k) * 128 + act + (col & 31) + 64 * (col >> 5)];
        }
    } else if (blk == Bn + 2) {
        if (tid < 128) {
            int l = tid >> 6, m = tid & 63;
            parv[tid]       = fb0[tid];
            parv[128 + tid] = fW0[(l * 65 + 64) * 64 + m];
            parv[256 + tid] = fb1[tid];
            int act = 32 * (1 - l);
            parv[384 + tid] = fb2[l * 128 + act + (m & 31) + 64 * (m >> 5)];
        }
        if (tid < 64) {
            int l = tid >> 5, i2 = tid & 31, act = 32 * (1 - l);
            parv[512 + tid] = ftw[l * 128 + act + i2];
            parv[576 + tid] = ftw[l * 128 + 64 + act + i2];
            parv[640 + tid] = Wi[tid];
            parv[704 + tid] = 0.f;
        }
    } else if (blk == Bn + 3) {
        for (int i = tid; i < 5120; i += 256) {
            int k = i % 40, m = (i / 40) & 63, l = i / 2560;
            float v = (k < 32) ? fW0[(l * 65 + 32 * l + k) * 64 + m] : 0.f;
            parwb[i] = f2b(v);
        }
    } else if (blk == Bn + 4) {
        for (int i = tid; i < 9216; i += 256) {
            int k = i % 72, m = (i / 72) & 63, l = i / 4608;
            float v = (k < 64) ? fW1[(l * 64 + k) * 64 + m] : 0.f;
            parwb[5120 + i] = f2b(v);
        }
    } else {
        for (int i = tid; i < 9216; i += 256) {
            int k = i % 72, m = (i / 72) & 63, l = i / 4608;
            int act = 32 * (1 - l);
            float v = (k < 64) ? fW2[(l * 64 + k) * 128 + act + (m & 31) + 64 * (m >> 5)] : 0.f;
            parwb[14336 + i] = f2b(v);
        }
    }
}

// ---------------------------------------------------------------------------
// Sequential kernel: one block (4 waves) per batch element. mv1/mv2/mv3 and
// coupling fully replicated per wave (all weights in registers, wave-private
// LDS broadcast buffers -> zero cross-wave hazards); only LSTM is split, with
// a double-buffered gate array -> ONE barrier per step. Next step's t-gate
// tanh's precomputed off the critical path.
extern "C" __global__ __launch_bounds__(256, 1)
void seq_kernel(const float* __restrict__ times, const float* __restrict__ mask,
                const float* __restrict__ fW0, const float* __restrict__ fb0,
                const float* __restrict__ fW1, const float* __restrict__ fb1,
                const float* __restrict__ fb2, const float* __restrict__ ftw,
                const float* __restrict__ Wi, const float* __restrict__ bi,
                const float* __restrict__ W_ih, const float* __restrict__ W_hh,
                const float* __restrict__ gc, const float* __restrict__ seqw2,
                const float* __restrict__ invd,
                float* __restrict__ h_carry, float* __restrict__ out)
{
    const int tid = threadIdx.x;
    const int j = tid & 63;
    const int w = tid >> 6;
    const int b = blockIdx.x;
    const bool w0 = (w == 0);

    __shared__ __align__(16) float xl[4][64];
    __shared__ __align__(16) float al[4][64];
    __shared__ __align__(16) float ssl[4][64];
    __shared__ float gl[2][256];

    float w0c[2][32], w0tc[2], b0c[2], w1c[2][64], b1c[2];
    float w2c[2][64], b2c[2], ftsc[2], ftsh[2];
    #pragma unroll
    for (int l = 0; l < 2; l++) {
        #pragma unroll
        for (int kk = 0; kk < 32; kk++)
            w0c[l][kk] = fW0[(l * 65 + 32 * l + kk) * 64 + j];
        w0tc[l] = fW0[(l * 65 + 64) * 64 + j];
        b0c[l]  = fb0[l * 64 + j];
        #pragma unroll
        for (int k = 0; k < 64; k++)
            w1c[l][k] = fW1[(l * 64 + k) * 64 + j];
        b1c[l] = fb1[l * 64 + j];
        #pragma unroll
        for (int k = 0; k < 64; k++)
            w2c[l][k] = seqw2[(l * 64 + k) * 64 + j];
        const int act = 32 * (1 - l);
        b2c[l]  = fb2[l * 128 + act + (j & 31) + 64 * (j >> 5)];
        ftsc[l] = ftw[l * 128 + j];
        ftsh[l] = ftw[l * 128 + 64 + j];
    }
    float whc[64];                 // LSTM: lane (w,j) owns gate w*64+j
    {
        const float4* src = (const float4*)(W_hh + (w * 64 + j) * 64);
        #pragma unroll
        for (int k4 = 0; k4 < 16; k4++) {
            float4 v = src[k4];
            whc[4 * k4 + 0] = v.x; whc[4 * k4 + 1] = v.y;
            whc[4 * k4 + 2] = v.z; whc[4 * k4 + 3] = v.w;
        }
    }
    const float gcr  = gc[b * 256 + w * 64 + j];
    const float wih0 = W_ih[(w * 64 + j) * 65];
    const float wij  = Wi[j];
    const float bi0  = bi[0];
    const float idn  = invd[0];

    float h = 0.f, c = 0.f, nllacc = 0.f;
    float tb = times[b * Tn];
    float mk = mask[b * Tn];
    float tscv[2], tshv[2];
    #pragma unroll
    for (int l = 0; l < 2; l++) {
        tscv[l] = tanhf_(tb * ftsc[l]);
        tshv[l] = tanhf_(tb * ftsh[l]);
    }

    for (int t = 0; t < Tn; t++) {
        const int tn = (t < Tn - 1) ? t + 1 : t;
        const float tb_n = times[b * Tn + tn];
        const float mk_n = mask[b * Tn + tn];

        if (w0) h_carry[(b * Tn + t) * 64 + j] = h;
        float x = h;
        xl[w][j] = x;
        #pragma unroll
        for (int l = 0; l < 2; l++) {
            const int kb  = 32 * l;
            const int act = 32 * (1 - l);
            // mv1 (replicated)
            float p0 = b0c[l] + tb * w0tc[l], p1 = 0.f, p2 = 0.f, p3 = 0.f;
            {
                const float4* xv4 = (const float4*)(&xl[w][kb]);
                #pragma unroll
                for (int k4 = 0; k4 < 8; k4++) {
                    float4 xv = xv4[k4];
                    p0 += xv.x * w0c[l][4 * k4 + 0];
                    p1 += xv.y * w0c[l][4 * k4 + 1];
                    p2 += xv.z * w0c[l][4 * k4 + 2];
                    p3 += xv.w * w0c[l][4 * k4 + 3];
                }
            }
            const float a1 = tanhf_((p0 + p1) + (p2 + p3));
            al[w][j] = a1;
            // mv2 (replicated)
            p0 = b1c[l]; p1 = p2 = p3 = 0.f;
            {
                const float4* av4 = (const float4*)(&al[w][0]);
                #pragma unroll
                for (int k4 = 0; k4 < 16; k4++) {
                    float4 av = av4[k4];
                    p0 += av.x * w1c[l][4 * k4 + 0];
                    p1 += av.y * w1c[l][4 * k4 + 1];
                    p2 += av.z * w1c[l][4 * k4 + 2];
                    p3 += av.w * w1c[l][4 * k4 + 3];
                }
            }
            const float a2 = tanhf_((p0 + p1) + (p2 + p3));
            al[w][j] = a2;     // all mv2 reads precede (in-order DS, same wave)
            // mv3 (replicated, register weight column for output col j)
            float s0 = b2c[l], s1 = 0.f, s2 = 0.f, s3 = 0.f;
            {
                const float4* av4 = (const float4*)(&al[w][0]);
                #pragma unroll
                for (int k4 = 0; k4 < 16; k4++) {
                    float4 av = av4[k4];
                    s0 += av.x * w2c[l][4 * k4 + 0];
                    s1 += av.y * w2c[l][4 * k4 + 1];
                    s2 += av.z * w2c[l][4 * k4 + 2];
                    s3 += av.w * w2c[l][4 * k4 + 3];
                }
            }
            ssl[w][j] = (s0 + s1) + (s2 + s3);
            // coupling (replicated, wave-private ssl -> no barrier)
            const int idx = (j - act) & 31;
            const float scl = ssl[w][idx];
            const float shf = ssl[w][idx + 32];
            const float xa  = x * __expf(scl * tscv[l]) + shf * tshv[l];
            const bool active = (l == 0) ? (j >= 32) : (j < 32);
            x = active ? xa : x;
            xl[w][j] = x;
        }
        if (w0) out[1 + (b * Tn + t) * 64 + j] = x;
        // nll
        float v = x * wij;
        #pragma unroll
        for (int off = 32; off >= 1; off >>= 1) v += __shfl_xor(v, off, 64);
        const float lam = softplusf_(v + bi0);
        if (w0) nllacc += -__logf(lam) * mk;
        // LSTM (split): lane (w,j) computes gate w*64+j; double-buffered gl
        float g0 = gcr + tb * wih0, g1 = 0.f, g2 = 0.f, g3 = 0.f;
        {
            const float4* hv4 = (const float4*)(&xl[w][0]);
            #pragma unroll
            for (int k4 = 0; k4 < 16; k4++) {
                float4 hv = hv4[k4];
                g0 += hv.x * whc[4 * k4 + 0];
                g1 += hv.y * whc[4 * k4 + 1];
                g2 += hv.z * whc[4 * k4 + 2];
                g3 += hv.w * whc[4 * k4 + 3];
            }
        }
        gl[t & 1][w * 64 + j] = (g0 + g1) + (g2 + g3);
        __syncthreads();
        const float gi = gl[t & 1][j],       gf = gl[t & 1][64 + j];
        const float gg = gl[t & 1][128 + j], go = gl[t & 1][192 + j];
        c = sigmoidf_(gf) * c + sigmoidf_(gi) * tanhf_(gg);
        h = sigmoidf_(go) * tanhf_(c);
        // next step's t-gates, off the critical path
        tscv[0] = tanhf_(tb_n * ftsc[0]); tshv[0] = tanhf_(tb_n * ftsh[0]);
        tscv[1] = tanhf_(tb_n * ftsc[1]); tshv[1] = tanhf_(tb_n * ftsh[1]);
        tb = tb_n; mk = mk_n;
    }
    if (tid == 0) atomicAdd(out, nllacc * idn);
}

// ---------------------------------------------------------------------------
// Parallel kernel, MFMA bf16. One wave = one (b,t) pair x 32 MC slots.
// A-frags stream from the global (L1/L2-resident) 46 KB weight image via
// dwordx4 loads (vmcnt, decoupled from the DS chain); LDS holds only
// wave-private activation rows (29 KB static) -> 4 blocks/CU, no barriers.
extern "C" __global__ __launch_bounds__(256, 4)
void par_kernel(const float* __restrict__ times, const float* __restrict__ mask,
                const float* __restrict__ u, const float* __restrict__ bi,
                const float* __restrict__ invd, const float* __restrict__ parv,
                const unsigned short* __restrict__ parwb,
                const float* __restrict__ h_carry, float* __restrict__ out)
{
    __shared__ __align__(16) unsigned short sact[128 * 72];
    __shared__ __align__(16) unsigned short sxk1[128 * 40];
    __shared__ __align__(16) unsigned short sx0b[4 * 40];

    const int tid = threadIdx.x, lane = tid & 63, w = tid >> 6;
    const int quad = lane >> 4, l15 = lane & 15;

    const int q = blockIdx.x * 4 + w;
    const int t = q >> 8, b = q & 255;
    const float tb = times[b * Tn + t];
    const float* hrow = h_carry + (b * Tn + t) * 64;
    if (lane < 32) sx0b[w * 40 + lane] = f2b(hrow[lane]);

    float tsv[2], sclf[2];
    {
        const float base = tb * (1.0f / 30.0f) * invd[0] * mask[b * Tn + t];
        #pragma unroll
        for (int nt = 0; nt < 2; nt++) {
            int mc = nt * 16 + l15;
            bool val = (mc < 30);
            tsv[nt]  = val ? u[t * MCn + mc] * tb : 0.f;
            sclf[nt] = val ? base : 0.f;
        }
    }
    f32x4 xr[2][4];
    #pragma unroll
    for (int mt = 0; mt < 4; mt++) {
        f32x4 v = *(const f32x4*)(hrow + mt * 16 + quad * 4);
        xr[0][mt] = v; xr[1][mt] = v;
    }
    const int srow = w * 32;

    #pragma unroll
    for (int l = 0; l < 2; l++) {
        const unsigned short* wA1 = parwb + l * 2560;
        const unsigned short* wA2 = parwb + 5120 + l * 4608;
        const unsigned short* wA3 = parwb + 14336 + l * 4608;
        // ---- mv1: K=32 ----
        f32x4 c1[4][2];
        if (l == 0) {
            bf16x8 bb = *(const bf16x8*)(sx0b + w * 40 + quad * 8);
            #pragma unroll
            for (int mt = 0; mt < 4; mt++) {
                bf16x8 af = *(const bf16x8*)(wA1 + (mt * 16 + l15) * 40 + quad * 8);
                f32x4 z = {0.f, 0.f, 0.f, 0.f};
                c1[mt][0] = __builtin_amdgcn_mfma_f32_16x16x32_bf16(af, bb, z, 0, 0, 0);
                c1[mt][1] = c1[mt][0];
            }
        } else {
            bf16x8 bf[2];
            #pragma unroll
            for (int nt = 0; nt < 2; nt++)
                bf[nt] = *(const bf16x8*)(sxk1 + (srow + nt * 16 + l15) * 40 + quad * 8);
            #pragma unroll
            for (int mt = 0; mt < 4; mt++) {
                bf16x8 af = *(const bf16x8*)(wA1 + (mt * 16 + l15) * 40 + quad * 8);
                #pragma unroll
                for (int nt = 0; nt < 2; nt++) {
                    f32x4 z = {0.f, 0.f, 0.f, 0.f};
                    c1[mt][nt] = __builtin_amdgcn_mfma_f32_16x16x32_bf16(af, bf[nt], z, 0, 0, 0);
                }
            }
        }
        // a1 = tanh(c1 + b0 + ts*w0t) -> sact
        #pragma unroll
        for (int mt = 0; mt < 4; mt++) {
            f32x4 b0r = *(const f32x4*)(parv + 0   + l * 64 + mt * 16 + quad * 4);
            f32x4 w0r = *(const f32x4*)(parv + 128 + l * 64 + mt * 16 + quad * 4);
            #pragma unroll
            for (int nt = 0; nt < 2; nt++) {
                float v0 = tanhf_(c1[mt][nt][0] + b0r[0] + tsv[nt] * w0r[0]);
                float v1 = tanhf_(c1[mt][nt][1] + b0r[1] + tsv[nt] * w0r[1]);
                float v2 = tanhf_(c1[mt][nt][2] + b0r[2] + tsv[nt] * w0r[2]);
                float v3 = tanhf_(c1[mt][nt][3] + b0r[3] + tsv[nt] * w0r[3]);
                uint2 pk; pk.x = pk2(v0, v1); pk.y = pk2(v2, v3);
                *(uint2*)(sact + (srow + nt * 16 + l15) * 72 + mt * 16 + quad * 4) = pk;
            }
        }
        // ---- mv2: K=64 ----
        f32x4 cc[4][2];
        #pragma unroll
        for (int mt = 0; mt < 4; mt++)
            #pragma unroll
            for (int nt = 0; nt < 2; nt++) cc[mt][nt] = (f32x4){0.f, 0.f, 0.f, 0.f};
        #pragma unroll
        for (int kt = 0; kt < 2; kt++) {
            bf16x8 bf[2];
            #pragma unroll
            for (int nt = 0; nt < 2; nt++)
                bf[nt] = *(const bf16x8*)(sact + (srow + nt * 16 + l15) * 72 + kt * 32 + quad * 8);
            #pragma unroll
            for (int mt = 0; mt < 4; mt++) {
                bf16x8 af = *(const bf16x8*)(wA2 + (mt * 16 + l15) * 72 + kt * 32 + quad * 8);
                #pragma unroll
                for (int nt = 0; nt < 2; nt++)
                    cc[mt][nt] = __builtin_amdgcn_mfma_f32_16x16x32_bf16(af, bf[nt], cc[mt][nt], 0, 0, 0);
            }
        }
        // a2 = tanh(cc + b1) -> sact
        #pragma unroll
        for (int mt = 0; mt < 4; mt++) {
            f32x4 b1r = *(const f32x4*)(parv + 256 + l * 64 + mt * 16 + quad * 4);
            #pragma unroll
            for (int nt = 0; nt < 2; nt++) {
                float v0 = tanhf_(cc[mt][nt][0] + b1r[0]);
                float v1 = tanhf_(cc[mt][nt][1] + b1r[1]);
                float v2 = tanhf_(cc[mt][nt][2] + b1r[2]);
                float v3 = tanhf_(cc[mt][nt][3] + b1r[3]);
                uint2 pk; pk.x = pk2(v0, v1); pk.y = pk2(v2, v3);
                *(uint2*)(sact + (srow + nt * 16 + l15) * 72 + mt * 16 + quad * 4) = pk;
            }
        }
        // ---- mv3: K=64 ----
        f32x4 ssf[4][2];
        #pragma unroll
        for (int mt = 0; mt < 4; mt++)
            #pragma unroll
            for (int nt = 0; nt < 2; nt++) ssf[mt][nt] = (f32x4){0.f, 0.f, 0.f, 0.f};
        #pragma unroll
        for (int kt = 0; kt < 2; kt++) {
            bf16x8 bf[2];
            #pragma unroll
            for (int nt = 0; nt < 2; nt++)
                bf[nt] = *(const bf16x8*)(sact + (srow + nt * 16 + l15) * 72 + kt * 32 + quad * 8);
            #pragma unroll
            for (int mt = 0; mt < 4; mt++) {
                bf16x8 af = *(const bf16x8*)(wA3 + (mt * 16 + l15) * 72 + kt * 32 + quad * 8);
                #pragma unroll
                for (int nt = 0; nt < 2; nt++)
                    ssf[mt][nt] = __builtin_amdgcn_mfma_f32_16x16x32_bf16(af, bf[nt], ssf[mt][nt], 0, 0, 0);
            }
        }
        // coupling in registers
        #pragma unroll
        for (int mt2 = 0; mt2 < 2; mt2++) {
            f32x4 b2s = *(const f32x4*)(parv + 384 + l * 64 +      mt2 * 16 + quad * 4);
            f32x4 b2h = *(const f32x4*)(parv + 384 + l * 64 + 32 + mt2 * 16 + quad * 4);
            f32x4 fa  = *(const f32x4*)(parv + 512 + l * 32 + mt2 * 16 + quad * 4);
            f32x4 fb  = *(const f32x4*)(parv + 576 + l * 32 + mt2 * 16 + quad * 4);
            const int xm = (l == 0) ? (mt2 + 2) : mt2;
            #pragma unroll
            for (int nt = 0; nt < 2; nt++) {
                #pragma unroll
                for (int r = 0; r < 4; r++) {
                    float sc  = ssf[mt2][nt][r] + b2s[r];
                    float sh  = ssf[mt2 + 2][nt][r] + b2h[r];
                    float tsc = tanhf_(tsv[nt] * fa[r]);
                    float tsh = tanhf_(tsv[nt] * fb[r]);
                    float xv  = xr[nt][xm][r];
                    xr[nt][xm][r] = xv * __expf(sc * tsc) + sh * tsh;
                }
                if (l == 0) {
                    uint2 pk;
                    pk.x = pk2(xr[nt][xm][0], xr[nt][xm][1]);
                    pk.y = pk2(xr[nt][xm][2], xr[nt][xm][3]);
                    *(uint2*)(sxk1 + (srow + nt * 16 + l15) * 40 + mt2 * 16 + quad * 4) = pk;
                }
            }
        }
    }
    // ---- intensity + loss ----
    float contrib = 0.f;
    const float bi0 = bi[0];
    #pragma unroll
    for (int nt = 0; nt < 2; nt++) {
        float d0 = 0.f, d1 = 0.f;
        #pragma unroll
        for (int mt = 0; mt < 4; mt++) {
            f32x4 wi4 = *(const f32x4*)(parv + 640 + mt * 16 + quad * 4);
            d0 += xr[nt][mt][0] * wi4[0] + xr[nt][mt][2] * wi4[2];
            d1 += xr[nt][mt][1] * wi4[1] + xr[nt][mt][3] * wi4[3];
        }
        float d = d0 + d1;
        d += __shfl_xor(d, 16, 64);
        d += __shfl_xor(d, 32, 64);
        contrib += softplusf_(d + bi0) * sclf[nt];
    }
    if (quad != 0) contrib = 0.f;
    #pragma unroll
    for (int off = 1; off <= 32; off <<= 1) contrib += __shfl_xor(contrib, off, 64);
    if (lane == 0) atomicAdd(out, contrib);
}

// ---------------------------------------------------------------------------
extern "C" void kernel_launch(void* const* d_in, const int* in_sizes, int n_in,
                              void* d_out, int out_size, void* d_ws, size_t ws_size,
                              hipStream_t stream)
{
    const float* times = (const float*)d_in[0];
    const int*   marks = (const int*)  d_in[1];
    const float* mask  = (const float*)d_in[2];
    const float* u     = (const float*)d_in[3];
    const float* emb   = (const float*)d_in[4];
    const float* fW0   = (const float*)d_in[5];
    const float* fb0   = (const float*)d_in[6];
    const float* fW1   = (const float*)d_in[7];
    const float* fb1   = (const float*)d_in[8];
    const float* fW2   = (const float*)d_in[9];
    const float* fb2   = (const float*)d_in[10];
    const float* ftw   = (const float*)d_in[11];
    const float* Wi    = (const float*)d_in[12];
    const float* bi    = (const float*)d_in[13];
    const float* W_ih  = (const float*)d_in[14];
    const float* W_hh  = (const float*)d_in[15];
    const float* b_ih  = (const float*)d_in[16];
    const float* b_hh  = (const float*)d_in[17];
    float* out = (float*)d_out;

    float* wsp     = (float*)d_ws;
    float* h_carry = wsp;                   // 2,097,152 floats
    float* gc      = h_carry + 2097152;     // 65,536
    float* invd    = gc + 65536;            // 4
    float* seqw2   = invd + 4;              // 8,192
    float* parv    = seqw2 + 8192;          // 768
    unsigned short* parwb = (unsigned short*)(parv + 768);   // 23,552 ushorts

    hipMemsetAsync(d_out, 0, sizeof(float), stream);

    prep_kernel<<<262, 256, 0, stream>>>(marks, mask, emb, fW0, fW1, fW2,
                                         fb0, fb1, fb2, ftw, Wi, W_ih,
                                         b_ih, b_hh, gc, invd, seqw2, parv, parwb);
    seq_kernel<<<Bn, 256, 0, stream>>>(times, mask, fW0, fb0, fW1, fb1,
                                       fb2, ftw, Wi, bi, W_ih, W_hh,
                                       gc, seqw2, invd, h_carry, out);
    par_kernel<<<(Bn * Tn) / 4, 256, 0, stream>>>(
        times, mask, u, bi, invd, parv, parwb, h_carry, out);
}

// Round 6
// 690.124 us; speedup vs baseline: 1.6343x; 1.6343x over previous
//
#include <hip/hip_runtime.h>
#include <hip/hip_bf16.h>
#include <math.h>

#define Bn   256
#define Tn   128
#define HID  64
#define MCn  30

typedef __attribute__((ext_vector_type(8))) short bf16x8;
typedef __attribute__((ext_vector_type(4))) float f32x4;

// ---------------------------------------------------------------------------
__device__ __forceinline__ float rcp_(float x) { return __builtin_amdgcn_rcpf(x); }
// tanh(x) = 2/(1+e^{-2x}) - 1 : 5 instrs, NaN-safe at both infinities
__device__ __forceinline__ float tanhf_(float x) {
    float e = __expf(-2.0f * x);
    return __builtin_fmaf(2.0f, rcp_(1.0f + e), -1.0f);
}
__device__ __forceinline__ float sigmoidf_(float x) {
    return rcp_(1.0f + __expf(-x));
}
__device__ __forceinline__ float softplusf_(float z) {
    float e = __expf(-fabsf(z));
    return fmaxf(z, 0.0f) + __logf(1.0f + e);
}
__device__ __forceinline__ unsigned short f2b(float f) {
    union { float f; unsigned u; } v; v.f = f;
    unsigned r = v.u + 0x7FFF + ((v.u >> 16) & 1);
    return (unsigned short)(r >> 16);
}
__device__ __forceinline__ unsigned pk2(float a, float b) {
    union { __hip_bfloat162 h2; unsigned u; } cv;
    cv.h2 = __float22bfloat162_rn(make_float2(a, b));
    return cv.u;
}

// ws images:
//  gc[b][256]                       : LSTM per-sample gate constants
//  parv (768 f32)                   : par vector block (see round-4 comment)
//  parwb (23552 bf16)               : par MFMA A-operand weight images
//  seqw1T[(l*64+j)*68+k] = fW1[l][k][j]                      (k<64, pad 0)
//  seqw2T[(l*64+j)*68+k] = fW2[l][k][act+(j&31)+64*(j>>5)]   (k<64, pad 0)
//  whh260[j*260+k*4+r]   = W_hh[(r*64+j)*64+k]               (k<64, pad 0)
extern "C" __global__ __launch_bounds__(256)
void prep_kernel(const int* __restrict__ marks, const float* __restrict__ mask,
                 const float* __restrict__ emb, const float* __restrict__ fW0,
                 const float* __restrict__ fW1, const float* __restrict__ fW2,
                 const float* __restrict__ fb0, const float* __restrict__ fb1,
                 const float* __restrict__ fb2, const float* __restrict__ ftw,
                 const float* __restrict__ Wi, const float* __restrict__ W_ih,
                 const float* __restrict__ W_hh,
                 const float* __restrict__ b_ih, const float* __restrict__ b_hh,
                 float* __restrict__ gc, float* __restrict__ invd,
                 float* __restrict__ parv, unsigned short* __restrict__ parwb,
                 float* __restrict__ seqw1T, float* __restrict__ seqw2T,
                 float* __restrict__ whh260)
{
    __shared__ float red[4];
    const int blk = blockIdx.x, tid = threadIdx.x;
    if (blk < Bn) {
        const int mark = marks[blk * Tn + 1];
        const float* er = emb + mark * HID;
        const float* wr = W_ih + tid * 65 + 1;
        float acc = b_ih[tid] + b_hh[tid];
        #pragma unroll
        for (int k = 0; k < HID; k++) acc += er[k] * wr[k];
        gc[blk * 256 + tid] = acc;
    } else if (blk == Bn) {
        float s = 0.f;
        for (int i = tid; i < Bn * Tn; i += 256) s += mask[i];
        #pragma unroll
        for (int off = 32; off >= 1; off >>= 1) s += __shfl_xor(s, off, 64);
        if ((tid & 63) == 0) red[tid >> 6] = s;
        __syncthreads();
        if (tid == 0) invd[0] = 1.0f / (red[0] + red[1] + red[2] + red[3]);
    } else if (blk == Bn + 1) {
        if (tid < 128) {
            int l = tid >> 6, m = tid & 63;
            parv[tid]       = fb0[tid];
            parv[128 + tid] = fW0[(l * 65 + 64) * 64 + m];
            parv[256 + tid] = fb1[tid];
            int act = 32 * (1 - l);
            parv[384 + tid] = fb2[l * 128 + act + (m & 31) + 64 * (m >> 5)];
        }
        if (tid < 64) {
            int l = tid >> 5, i2 = tid & 31, act = 32 * (1 - l);
            parv[512 + tid] = ftw[l * 128 + act + i2];
            parv[576 + tid] = ftw[l * 128 + 64 + act + i2];
            parv[640 + tid] = Wi[tid];
            parv[704 + tid] = 0.f;
        }
    } else if (blk == Bn + 2) {
        for (int i = tid; i < 5120; i += 256) {
            int k = i % 40, m = (i / 40) & 63, l = i / 2560;
            float v = (k < 32) ? fW0[(l * 65 + 32 * l + k) * 64 + m] : 0.f;
            parwb[i] = f2b(v);
        }
    } else if (blk == Bn + 3) {
        for (int i = tid; i < 9216; i += 256) {
            int k = i % 72, m = (i / 72) & 63, l = i / 4608;
            float v = (k < 64) ? fW1[(l * 64 + k) * 64 + m] : 0.f;
            parwb[5120 + i] = f2b(v);
        }
    } else if (blk == Bn + 4) {
        for (int i = tid; i < 9216; i += 256) {
            int k = i % 72, m = (i / 72) & 63, l = i / 4608;
            int act = 32 * (1 - l);
            float v = (k < 64) ? fW2[(l * 64 + k) * 128 + act + (m & 31) + 64 * (m >> 5)] : 0.f;
            parwb[14336 + i] = f2b(v);
        }
    } else if (blk == Bn + 5) {
        for (int i = tid; i < 8704; i += 256) {
            int k = i % 68, j = (i / 68) & 63, l = i / 4352;
            seqw1T[i] = (k < 64) ? fW1[(l * 64 + k) * 64 + j] : 0.f;
        }
    } else if (blk == Bn + 6) {
        for (int i = tid; i < 8704; i += 256) {
            int k = i % 68, j = (i / 68) & 63, l = i / 4352;
            int act = 32 * (1 - l);
            seqw2T[i] = (k < 64) ?
                fW2[(l * 64 + k) * 128 + act + (j & 31) + 64 * (j >> 5)] : 0.f;
        }
    } else {
        for (int i = tid; i < 16640; i += 256) {
            int j = i / 260, rem = i % 260, k = rem >> 2, r = rem & 3;
            whh260[i] = (k < 64) ? W_hh[(r * 64 + j) * 64 + k] : 0.f;
        }
    }
}

// ---------------------------------------------------------------------------
// Sequential kernel: ONE wave per batch element, ZERO barriers, spill-free.
// Only w0 columns (64 regs) + biases live in registers; w1/w2/W_hh streams in
// LDS (strides 68/260 — measured 0 bank conflicts in round 2); times/mask
// preloaded to LDS; h_carry/h2 global stores are fire-and-forget (no barrier
// -> no vmcnt drain). 138 KB dynamic LDS, 1 block/CU.
extern "C" __global__ __launch_bounds__(64, 1)
void seq_kernel(const float* __restrict__ times, const float* __restrict__ mask,
                const float* __restrict__ fW0, const float* __restrict__ fb0,
                const float* __restrict__ fb1, const float* __restrict__ fb2,
                const float* __restrict__ ftw, const float* __restrict__ Wi,
                const float* __restrict__ bi, const float* __restrict__ W_ih,
                const float* __restrict__ gc, const float* __restrict__ seqw1T,
                const float* __restrict__ invd,
                float* __restrict__ h_carry, float* __restrict__ out)
{
    const int j = threadIdx.x;
    const int b = blockIdx.x;

    extern __shared__ float smem[];
    float* w1l  = smem;              // 8704  : w1T, stride 68
    float* w2l  = smem + 8704;       // 8704  : w2T, stride 68
    float* whhl = smem + 17408;      // 16640 : whh260
    float* tl   = smem + 34048;      // 128
    float* ml   = smem + 34176;      // 128
    float* xl   = smem + 34304;      // 64
    float* al   = smem + 34368;      // 64
    float* ssl  = smem + 34432;      // 64   (total 34496 floats = 137984 B)

    // stage the three contiguous weight images (8512 float4)
    {
        const float4* s = (const float4*)seqw1T;
        float4* d = (float4*)smem;
        for (int i = j; i < 8512; i += 64) d[i] = s[i];
    }
    tl[j] = times[b * Tn + j];       tl[j + 64] = times[b * Tn + 64 + j];
    ml[j] = mask[b * Tn + j];        ml[j + 64] = mask[b * Tn + 64 + j];

    // per-lane registers: ONLY small arrays (no spill)
    float w0c[2][32], w0tc[2], b0c[2], b1c[2], b2c[2], ftsc[2], ftsh[2];
    #pragma unroll
    for (int l = 0; l < 2; l++) {
        #pragma unroll
        for (int kk = 0; kk < 32; kk++)
            w0c[l][kk] = fW0[(l * 65 + 32 * l + kk) * 64 + j];
        w0tc[l] = fW0[(l * 65 + 64) * 64 + j];
        b0c[l]  = fb0[l * 64 + j];
        b1c[l]  = fb1[l * 64 + j];
        const int act = 32 * (1 - l);
        b2c[l]  = fb2[l * 128 + act + (j & 31) + 64 * (j >> 5)];
        ftsc[l] = ftw[l * 128 + j];
        ftsh[l] = ftw[l * 128 + 64 + j];
    }
    const float wij = Wi[j];
    const float bi0 = bi[0];
    float wih0[4], gcr[4];
    #pragma unroll
    for (int r = 0; r < 4; r++) {
        wih0[r] = W_ih[(r * 64 + j) * 65];
        gcr[r]  = gc[b * 256 + r * 64 + j];
    }
    const float idn = invd[0];

    float h = 0.f, c = 0.f, nllacc = 0.f;
    for (int t = 0; t < Tn; t++) {
        const float tb = tl[t];
        // t-gate tanh's issued early (consumed after mv3)
        float tscv[2], tshv[2];
        #pragma unroll
        for (int l = 0; l < 2; l++) {
            tscv[l] = tanhf_(tb * ftsc[l]);
            tshv[l] = tanhf_(tb * ftsh[l]);
        }
        h_carry[(b * Tn + t) * 64 + j] = h;      // fire-and-forget
        float x = h;
        xl[j] = x;
        #pragma unroll
        for (int l = 0; l < 2; l++) {
            const int kb  = 32 * l;
            const int act = 32 * (1 - l);
            // mv1: register weights, broadcast acts
            float p0 = b0c[l] + tb * w0tc[l], p1 = 0.f, p2 = 0.f, p3 = 0.f;
            {
                const float4* xv4 = (const float4*)(xl + kb);
                #pragma unroll
                for (int k4 = 0; k4 < 8; k4++) {
                    float4 xv = xv4[k4];
                    p0 += xv.x * w0c[l][4 * k4 + 0];
                    p1 += xv.y * w0c[l][4 * k4 + 1];
                    p2 += xv.z * w0c[l][4 * k4 + 2];
                    p3 += xv.w * w0c[l][4 * k4 + 3];
                }
            }
            al[j] = tanhf_((p0 + p1) + (p2 + p3));
            // mv2: LDS weight stream (stride 68) x broadcast acts
            p0 = b1c[l]; p1 = p2 = p3 = 0.f;
            {
                const float4* av4 = (const float4*)al;
                const float*  wp  = w1l + (l * 64 + j) * 68;
                #pragma unroll
                for (int k4 = 0; k4 < 16; k4++) {
                    float4 av = av4[k4];
                    float4 wv = *(const float4*)(wp + 4 * k4);
                    p0 += av.x * wv.x;
                    p1 += av.y * wv.y;
                    p2 += av.z * wv.z;
                    p3 += av.w * wv.w;
                }
            }
            al[j] = tanhf_((p0 + p1) + (p2 + p3));   // in-order DS: reads precede
            // mv3: LDS weight stream (stride 68)
            p0 = b2c[l]; p1 = p2 = p3 = 0.f;
            {
                const float4* av4 = (const float4*)al;
                const float*  wp  = w2l + (l * 64 + j) * 68;
                #pragma unroll
                for (int k4 = 0; k4 < 16; k4++) {
                    float4 av = av4[k4];
                    float4 wv = *(const float4*)(wp + 4 * k4);
                    p0 += av.x * wv.x;
                    p1 += av.y * wv.y;
                    p2 += av.z * wv.z;
                    p3 += av.w * wv.w;
                }
            }
            ssl[j] = (p0 + p1) + (p2 + p3);
            // coupling (2 lanes/bank reads = conflict-free)
            const int idx = (j - act) & 31;
            const float scl = ssl[idx];
            const float shf = ssl[idx + 32];
            const float xa  = x * __expf(scl * tscv[l]) + shf * tshv[l];
            const bool active = (l == 0) ? (j >= 32) : (j < 32);
            x = active ? xa : x;
            xl[j] = x;
        }
        out[1 + (b * Tn + t) * 64 + j] = x;      // h2, fire-and-forget
        // nll
        float v = x * wij;
        #pragma unroll
        for (int off = 32; off >= 1; off >>= 1) v += __shfl_xor(v, off, 64);
        nllacc += -__logf(softplusf_(v + bi0)) * ml[t];
        // LSTM: lane j owns gates {j, 64+j, 128+j, 192+j}; weights from LDS
        float g0 = gcr[0] + tb * wih0[0];
        float g1 = gcr[1] + tb * wih0[1];
        float g2 = gcr[2] + tb * wih0[2];
        float g3 = gcr[3] + tb * wih0[3];
        {
            const float*  wr_base = whhl + j * 260;
            const float4* hv4 = (const float4*)xl;
            #pragma unroll
            for (int k4 = 0; k4 < 16; k4++) {
                float4 hv = hv4[k4];
                const float* wr = wr_base + 16 * k4;
                float4 wa = *(const float4*)(wr);
                float4 wb = *(const float4*)(wr + 4);
                float4 wc = *(const float4*)(wr + 8);
                float4 wd = *(const float4*)(wr + 12);
                g0 += hv.x * wa.x; g1 += hv.x * wa.y; g2 += hv.x * wa.z; g3 += hv.x * wa.w;
                g0 += hv.y * wb.x; g1 += hv.y * wb.y; g2 += hv.y * wb.z; g3 += hv.y * wb.w;
                g0 += hv.z * wc.x; g1 += hv.z * wc.y; g2 += hv.z * wc.z; g3 += hv.z * wc.w;
                g0 += hv.w * wd.x; g1 += hv.w * wd.y; g2 += hv.w * wd.z; g3 += hv.w * wd.w;
            }
        }
        c = sigmoidf_(g1) * c + sigmoidf_(g0) * tanhf_(g2);
        h = sigmoidf_(g3) * tanhf_(c);
    }
    if (j == 0) atomicAdd(out, nllacc * idn);
}

// ---------------------------------------------------------------------------
// Parallel kernel, MFMA bf16 (round-4/5 math). Weights stream from the global
// 46 KB bf16 image (L1/L2 resident, vmcnt-decoupled); LDS holds only
// wave-private activation rows (~29 KB). __launch_bounds__(256,2): VGPR cap
// 256 -> NO spill (round-5's cap 128 spilled). Loss partial per BLOCK written
// to pp[] (no same-address atomic storm); fin_kernel reduces.
extern "C" __global__ __launch_bounds__(256, 2)
void par_kernel(const float* __restrict__ times, const float* __restrict__ mask,
                const float* __restrict__ u, const float* __restrict__ bi,
                const float* __restrict__ invd, const float* __restrict__ parv,
                const unsigned short* __restrict__ parwb,
                const float* __restrict__ h_carry, float* __restrict__ pp)
{
    __shared__ __align__(16) unsigned short sact[128 * 72];
    __shared__ __align__(16) unsigned short sxk1[128 * 40];
    __shared__ __align__(16) unsigned short sx0b[4 * 40];
    __shared__ float pr[4];

    const int tid = threadIdx.x, lane = tid & 63, w = tid >> 6;
    const int quad = lane >> 4, l15 = lane & 15;

    const int q = blockIdx.x * 4 + w;
    const int t = q >> 8, b = q & 255;
    const float tb = times[b * Tn + t];
    const float* hrow = h_carry + (b * Tn + t) * 64;
    if (lane < 32) sx0b[w * 40 + lane] = f2b(hrow[lane]);

    float tsv[2], sclf[2];
    {
        const float base = tb * (1.0f / 30.0f) * invd[0] * mask[b * Tn + t];
        #pragma unroll
        for (int nt = 0; nt < 2; nt++) {
            int mc = nt * 16 + l15;
            bool val = (mc < 30);
            tsv[nt]  = val ? u[t * MCn + mc] * tb : 0.f;
            sclf[nt] = val ? base : 0.f;
        }
    }
    f32x4 xr[2][4];
    #pragma unroll
    for (int mt = 0; mt < 4; mt++) {
        f32x4 v = *(const f32x4*)(hrow + mt * 16 + quad * 4);
        xr[0][mt] = v; xr[1][mt] = v;
    }
    const int srow = w * 32;

    #pragma unroll
    for (int l = 0; l < 2; l++) {
        const unsigned short* wA1 = parwb + l * 2560;
        const unsigned short* wA2 = parwb + 5120 + l * 4608;
        const unsigned short* wA3 = parwb + 14336 + l * 4608;
        // ---- mv1: K=32 ----
        f32x4 c1[4][2];
        if (l == 0) {
            bf16x8 bb = *(const bf16x8*)(sx0b + w * 40 + quad * 8);
            #pragma unroll
            for (int mt = 0; mt < 4; mt++) {
                bf16x8 af = *(const bf16x8*)(wA1 + (mt * 16 + l15) * 40 + quad * 8);
                f32x4 z = {0.f, 0.f, 0.f, 0.f};
                c1[mt][0] = __builtin_amdgcn_mfma_f32_16x16x32_bf16(af, bb, z, 0, 0, 0);
                c1[mt][1] = c1[mt][0];
            }
        } else {
            bf16x8 bf[2];
            #pragma unroll
            for (int nt = 0; nt < 2; nt++)
                bf[nt] = *(const bf16x8*)(sxk1 + (srow + nt * 16 + l15) * 40 + quad * 8);
            #pragma unroll
            for (int mt = 0; mt < 4; mt++) {
                bf16x8 af = *(const bf16x8*)(wA1 + (mt * 16 + l15) * 40 + quad * 8);
                #pragma unroll
                for (int nt = 0; nt < 2; nt++) {
                    f32x4 z = {0.f, 0.f, 0.f, 0.f};
                    c1[mt][nt] = __builtin_amdgcn_mfma_f32_16x16x32_bf16(af, bf[nt], z, 0, 0, 0);
                }
            }
        }
        #pragma unroll
        for (int mt = 0; mt < 4; mt++) {
            f32x4 b0r = *(const f32x4*)(parv + 0   + l * 64 + mt * 16 + quad * 4);
            f32x4 w0r = *(const f32x4*)(parv + 128 + l * 64 + mt * 16 + quad * 4);
            #pragma unroll
            for (int nt = 0; nt < 2; nt++) {
                float v0 = tanhf_(c1[mt][nt][0] + b0r[0] + tsv[nt] * w0r[0]);
                float v1 = tanhf_(c1[mt][nt][1] + b0r[1] + tsv[nt] * w0r[1]);
                float v2 = tanhf_(c1[mt][nt][2] + b0r[2] + tsv[nt] * w0r[2]);
                float v3 = tanhf_(c1[mt][nt][3] + b0r[3] + tsv[nt] * w0r[3]);
                uint2 pk; pk.x = pk2(v0, v1); pk.y = pk2(v2, v3);
                *(uint2*)(sact + (srow + nt * 16 + l15) * 72 + mt * 16 + quad * 4) = pk;
            }
        }
        // ---- mv2: K=64 ----
        f32x4 cc[4][2];
        #pragma unroll
        for (int mt = 0; mt < 4; mt++)
            #pragma unroll
            for (int nt = 0; nt < 2; nt++) cc[mt][nt] = (f32x4){0.f, 0.f, 0.f, 0.f};
        #pragma unroll
        for (int kt = 0; kt < 2; kt++) {
            bf16x8 bf[2];
            #pragma unroll
            for (int nt = 0; nt < 2; nt++)
                bf[nt] = *(const bf16x8*)(sact + (srow + nt * 16 + l15) * 72 + kt * 32 + quad * 8);
            #pragma unroll
            for (int mt = 0; mt < 4; mt++) {
                bf16x8 af = *(const bf16x8*)(wA2 + (mt * 16 + l15) * 72 + kt * 32 + quad * 8);
                #pragma unroll
                for (int nt = 0; nt < 2; nt++)
                    cc[mt][nt] = __builtin_amdgcn_mfma_f32_16x16x32_bf16(af, bf[nt], cc[mt][nt], 0, 0, 0);
            }
        }
        #pragma unroll
        for (int mt = 0; mt < 4; mt++) {
            f32x4 b1r = *(const f32x4*)(parv + 256 + l * 64 + mt * 16 + quad * 4);
            #pragma unroll
            for (int nt = 0; nt < 2; nt++) {
                float v0 = tanhf_(cc[mt][nt][0] + b1r[0]);
                float v1 = tanhf_(cc[mt][nt][1] + b1r[1]);
                float v2 = tanhf_(cc[mt][nt][2] + b1r[2]);
                float v3 = tanhf_(cc[mt][nt][3] + b1r[3]);
                uint2 pk; pk.x = pk2(v0, v1); pk.y = pk2(v2, v3);
                *(uint2*)(sact + (srow + nt * 16 + l15) * 72 + mt * 16 + quad * 4) = pk;
            }
        }
        // ---- mv3: K=64 ----
        f32x4 ssf[4][2];
        #pragma unroll
        for (int mt = 0; mt < 4; mt++)
            #pragma unroll
            for (int nt = 0; nt < 2; nt++) ssf[mt][nt] = (f32x4){0.f, 0.f, 0.f, 0.f};
        #pragma unroll
        for (int kt = 0; kt < 2; kt++) {
            bf16x8 bf[2];
            #pragma unroll
            for (int nt = 0; nt < 2; nt++)
                bf[nt] = *(const bf16x8*)(sact + (srow + nt * 16 + l15) * 72 + kt * 32 + quad * 8);
            #pragma unroll
            for (int mt = 0; mt < 4; mt++) {
                bf16x8 af = *(const bf16x8*)(wA3 + (mt * 16 + l15) * 72 + kt * 32 + quad * 8);
                #pragma unroll
                for (int nt = 0; nt < 2; nt++)
                    ssf[mt][nt] = __builtin_amdgcn_mfma_f32_16x16x32_bf16(af, bf[nt], ssf[mt][nt], 0, 0, 0);
            }
        }
        // coupling in registers
        #pragma unroll
        for (int mt2 = 0; mt2 < 2; mt2++) {
            f32x4 b2s = *(const f32x4*)(parv + 384 + l * 64 +      mt2 * 16 + quad * 4);
            f32x4 b2h = *(const f32x4*)(parv + 384 + l * 64 + 32 + mt2 * 16 + quad * 4);
            f32x4 fa  = *(const f32x4*)(parv + 512 + l * 32 + mt2 * 16 + quad * 4);
            f32x4 fb  = *(const f32x4*)(parv + 576 + l * 32 + mt2 * 16 + quad * 4);
            const int xm = (l == 0) ? (mt2 + 2) : mt2;
            #pragma unroll
            for (int nt = 0; nt < 2; nt++) {
                #pragma unroll
                for (int r = 0; r < 4; r++) {
                    float sc  = ssf[mt2][nt][r] + b2s[r];
                    float sh  = ssf[mt2 + 2][nt][r] + b2h[r];
                    float tsc = tanhf_(tsv[nt] * fa[r]);
                    float tsh = tanhf_(tsv[nt] * fb[r]);
                    float xv  = xr[nt][xm][r];
                    xr[nt][xm][r] = xv * __expf(sc * tsc) + sh * tsh;
                }
                if (l == 0) {
                    uint2 pk;
                    pk.x = pk2(xr[nt][xm][0], xr[nt][xm][1]);
                    pk.y = pk2(xr[nt][xm][2], xr[nt][xm][3]);
                    *(uint2*)(sxk1 + (srow + nt * 16 + l15) * 40 + mt2 * 16 + quad * 4) = pk;
                }
            }
        }
    }
    // ---- intensity + per-block loss partial ----
    float contrib = 0.f;
    const float bi0 = bi[0];
    #pragma unroll
    for (int nt = 0; nt < 2; nt++) {
        float d0 = 0.f, d1 = 0.f;
        #pragma unroll
        for (int mt = 0; mt < 4; mt++) {
            f32x4 wi4 = *(const f32x4*)(parv + 640 + mt * 16 + quad * 4);
            d0 += xr[nt][mt][0] * wi4[0] + xr[nt][mt][2] * wi4[2];
            d1 += xr[nt][mt][1] * wi4[1] + xr[nt][mt][3] * wi4[3];
        }
        float d = d0 + d1;
        d += __shfl_xor(d, 16, 64);
        d += __shfl_xor(d, 32, 64);
        contrib += softplusf_(d + bi0) * sclf[nt];
    }
    if (quad != 0) contrib = 0.f;
    #pragma unroll
    for (int off = 1; off <= 8; off <<= 1) contrib += __shfl_xor(contrib, off, 64);
    if (l15 == 0 && quad == 0) pr[w] = contrib;
    __syncthreads();
    if (tid == 0) pp[blockIdx.x] = pr[0] + pr[1] + pr[2] + pr[3];
}

// ---------------------------------------------------------------------------
extern "C" __global__ __launch_bounds__(256)
void fin_kernel(const float* __restrict__ pp, float* __restrict__ out)
{
    __shared__ float r4[4];
    const int tid = threadIdx.x;
    float s = 0.f;
    for (int i = tid; i < (Bn * Tn) / 4; i += 256) s += pp[i];
    #pragma unroll
    for (int off = 32; off >= 1; off >>= 1) s += __shfl_xor(s, off, 64);
    if ((tid & 63) == 0) r4[tid >> 6] = s;
    __syncthreads();
    if (tid == 0) atomicAdd(out, r4[0] + r4[1] + r4[2] + r4[3]);
}

// ---------------------------------------------------------------------------
extern "C" void kernel_launch(void* const* d_in, const int* in_sizes, int n_in,
                              void* d_out, int out_size, void* d_ws, size_t ws_size,
                              hipStream_t stream)
{
    const float* times = (const float*)d_in[0];
    const int*   marks = (const int*)  d_in[1];
    const float* mask  = (const float*)d_in[2];
    const float* u     = (const float*)d_in[3];
    const float* emb   = (const float*)d_in[4];
    const float* fW0   = (const float*)d_in[5];
    const float* fb0   = (const float*)d_in[6];
    const float* fW1   = (const float*)d_in[7];
    const float* fb1   = (const float*)d_in[8];
    const float* fW2   = (const float*)d_in[9];
    const float* fb2   = (const float*)d_in[10];
    const float* ftw   = (const float*)d_in[11];
    const float* Wi    = (const float*)d_in[12];
    const float* bi    = (const float*)d_in[13];
    const float* W_ih  = (const float*)d_in[14];
    const float* W_hh  = (const float*)d_in[15];
    const float* b_ih  = (const float*)d_in[16];
    const float* b_hh  = (const float*)d_in[17];
    float* out = (float*)d_out;

    float* wsp     = (float*)d_ws;
    float* h_carry = wsp;                   // 2,097,152
    float* gc      = h_carry + 2097152;     // 65,536
    float* invd    = gc + 65536;            // 4
    float* seqw1T  = invd + 4;              // 8,704  (w1l/w2l/whhl contiguous)
    float* seqw2T  = seqw1T + 8704;         // 8,704
    float* whh260  = seqw2T + 8704;         // 16,640
    float* parv    = whh260 + 16640;        // 768
    unsigned short* parwb = (unsigned short*)(parv + 768);   // 23,552 ushorts
    float* pp      = (float*)(parwb + 23552);                // 8,192

    hipMemsetAsync(d_out, 0, sizeof(float), stream);

    const int SEQ_SMEM = 34496 * 4;   // 137,984 B
    hipFuncSetAttribute((const void*)seq_kernel,
                        hipFuncAttributeMaxDynamicSharedMemorySize, SEQ_SMEM);

    prep_kernel<<<Bn + 8, 256, 0, stream>>>(marks, mask, emb, fW0, fW1, fW2,
                                            fb0, fb1, fb2, ftw, Wi, W_ih, W_hh,
                                            b_ih, b_hh, gc, invd, parv, parwb,
                                            seqw1T, seqw2T, whh260);
    seq_kernel<<<Bn, 64, SEQ_SMEM, stream>>>(times, mask, fW0, fb0, fb1, fb2,
                                             ftw, Wi, bi, W_ih, gc, seqw1T,
                                             invd, h_carry, out);
    par_kernel<<<(Bn * Tn) / 4, 256, 0, stream>>>(
        times, mask, u, bi, invd, parv, parwb, h_carry, pp);
    fin_kernel<<<1, 256, 0, stream>>>(pp, out);
}

// Round 7
// 687.619 us; speedup vs baseline: 1.6403x; 1.0036x over previous
//
#include <hip/hip_runtime.h>
#include <hip/hip_bf16.h>
#include <math.h>

#define Bn   256
#define Tn   128
#define HID  64
#define MCn  30

typedef __attribute__((ext_vector_type(8))) short bf16x8;
typedef __attribute__((ext_vector_type(4))) float f32x4;

// ---------------------------------------------------------------------------
__device__ __forceinline__ float rcp_(float x) { return __builtin_amdgcn_rcpf(x); }
// tanh(x) = 2/(1+e^{-2x}) - 1 : 5 instrs, NaN-safe at both infinities
__device__ __forceinline__ float tanhf_(float x) {
    float e = __expf(-2.0f * x);
    return __builtin_fmaf(2.0f, rcp_(1.0f + e), -1.0f);
}
__device__ __forceinline__ float sigmoidf_(float x) {
    return rcp_(1.0f + __expf(-x));
}
__device__ __forceinline__ float softplusf_(float z) {
    float e = __expf(-fabsf(z));
    return fmaxf(z, 0.0f) + __logf(1.0f + e);
}
__device__ __forceinline__ unsigned short f2b(float f) {
    union { float f; unsigned u; } v; v.f = f;
    unsigned r = v.u + 0x7FFF + ((v.u >> 16) & 1);
    return (unsigned short)(r >> 16);
}
__device__ __forceinline__ unsigned pk2(float a, float b) {
    union { __hip_bfloat162 h2; unsigned u; } cv;
    cv.h2 = __float22bfloat162_rn(make_float2(a, b));
    return cv.u;
}

// ws images (same as round 6):
//  gc[b][256], parv (768 f32), parwb (23552 bf16),
//  seqw1T[(l*64+j)*68+k] = fW1[l][k][j]
//  seqw2T[(l*64+j)*68+k] = fW2[l][k][act+(j&31)+64*(j>>5)]
//  whh260[j*260+k*4+r]   = W_hh[(r*64+j)*64+k]
extern "C" __global__ __launch_bounds__(256)
void prep_kernel(const int* __restrict__ marks, const float* __restrict__ mask,
                 const float* __restrict__ emb, const float* __restrict__ fW0,
                 const float* __restrict__ fW1, const float* __restrict__ fW2,
                 const float* __restrict__ fb0, const float* __restrict__ fb1,
                 const float* __restrict__ fb2, const float* __restrict__ ftw,
                 const float* __restrict__ Wi, const float* __restrict__ W_ih,
                 const float* __restrict__ W_hh,
                 const float* __restrict__ b_ih, const float* __restrict__ b_hh,
                 float* __restrict__ gc, float* __restrict__ invd,
                 float* __restrict__ parv, unsigned short* __restrict__ parwb,
                 float* __restrict__ seqw1T, float* __restrict__ seqw2T,
                 float* __restrict__ whh260)
{
    __shared__ float red[4];
    const int blk = blockIdx.x, tid = threadIdx.x;
    if (blk < Bn) {
        const int mark = marks[blk * Tn + 1];
        const float* er = emb + mark * HID;
        const float* wr = W_ih + tid * 65 + 1;
        float acc = b_ih[tid] + b_hh[tid];
        #pragma unroll
        for (int k = 0; k < HID; k++) acc += er[k] * wr[k];
        gc[blk * 256 + tid] = acc;
    } else if (blk == Bn) {
        float s = 0.f;
        for (int i = tid; i < Bn * Tn; i += 256) s += mask[i];
        #pragma unroll
        for (int off = 32; off >= 1; off >>= 1) s += __shfl_xor(s, off, 64);
        if ((tid & 63) == 0) red[tid >> 6] = s;
        __syncthreads();
        if (tid == 0) invd[0] = 1.0f / (red[0] + red[1] + red[2] + red[3]);
    } else if (blk == Bn + 1) {
        if (tid < 128) {
            int l = tid >> 6, m = tid & 63;
            parv[tid]       = fb0[tid];
            parv[128 + tid] = fW0[(l * 65 + 64) * 64 + m];
            parv[256 + tid] = fb1[tid];
            int act = 32 * (1 - l);
            parv[384 + tid] = fb2[l * 128 + act + (m & 31) + 64 * (m >> 5)];
        }
        if (tid < 64) {
            int l = tid >> 5, i2 = tid & 31, act = 32 * (1 - l);
            parv[512 + tid] = ftw[l * 128 + act + i2];
            parv[576 + tid] = ftw[l * 128 + 64 + act + i2];
            parv[640 + tid] = Wi[tid];
            parv[704 + tid] = 0.f;
        }
    } else if (blk == Bn + 2) {
        for (int i = tid; i < 5120; i += 256) {
            int k = i % 40, m = (i / 40) & 63, l = i / 2560;
            float v = (k < 32) ? fW0[(l * 65 + 32 * l + k) * 64 + m] : 0.f;
            parwb[i] = f2b(v);
        }
    } else if (blk == Bn + 3) {
        for (int i = tid; i < 9216; i += 256) {
            int k = i % 72, m = (i / 72) & 63, l = i / 4608;
            float v = (k < 64) ? fW1[(l * 64 + k) * 64 + m] : 0.f;
            parwb[5120 + i] = f2b(v);
        }
    } else if (blk == Bn + 4) {
        for (int i = tid; i < 9216; i += 256) {
            int k = i % 72, m = (i / 72) & 63, l = i / 4608;
            int act = 32 * (1 - l);
            float v = (k < 64) ? fW2[(l * 64 + k) * 128 + act + (m & 31) + 64 * (m >> 5)] : 0.f;
            parwb[14336 + i] = f2b(v);
        }
    } else if (blk == Bn + 5) {
        for (int i = tid; i < 8704; i += 256) {
            int k = i % 68, j = (i / 68) & 63, l = i / 4352;
            seqw1T[i] = (k < 64) ? fW1[(l * 64 + k) * 64 + j] : 0.f;
        }
    } else if (blk == Bn + 6) {
        for (int i = tid; i < 8704; i += 256) {
            int k = i % 68, j = (i / 68) & 63, l = i / 4352;
            int act = 32 * (1 - l);
            seqw2T[i] = (k < 64) ?
                fW2[(l * 64 + k) * 128 + act + (j & 31) + 64 * (j >> 5)] : 0.f;
        }
    } else {
        for (int i = tid; i < 16640; i += 256) {
            int j = i / 260, rem = i % 260, k = rem >> 2, r = rem & 3;
            whh260[i] = (k < 64) ? W_hh[(r * 64 + j) * 64 + k] : 0.f;
        }
    }
}

// ---------------------------------------------------------------------------
// Sequential kernel: ONE wave per batch element, zero barriers, and BATCHED
// two-phase matvecs: each stage issues all its ds_read_b128 into register
// arrays (float4 av[16]/wv[16], ~128 VGPRs of load buffer) before the FMA
// block, so the DS pipe streams at throughput instead of load->wait->FMA
// serialization (round-6's VGPR=88 showed the compiler chose shallow depth).
extern "C" __global__ __launch_bounds__(64, 1)
void seq_kernel(const float* __restrict__ times, const float* __restrict__ mask,
                const float* __restrict__ fW0, const float* __restrict__ fb0,
                const float* __restrict__ fb1, const float* __restrict__ fb2,
                const float* __restrict__ ftw, const float* __restrict__ Wi,
                const float* __restrict__ bi, const float* __restrict__ W_ih,
                const float* __restrict__ gc, const float* __restrict__ seqw1T,
                const float* __restrict__ invd,
                float* __restrict__ h_carry, float* __restrict__ out)
{
    const int j = threadIdx.x;
    const int b = blockIdx.x;

    extern __shared__ float smem[];
    float* w1l  = smem;              // 8704  : w1T, stride 68
    float* w2l  = smem + 8704;       // 8704  : w2T, stride 68
    float* whhl = smem + 17408;      // 16640 : whh260
    float* tl   = smem + 34048;      // 128
    float* ml   = smem + 34176;      // 128
    float* xl   = smem + 34304;      // 64
    float* al   = smem + 34368;      // 64
    float* ssl  = smem + 34432;      // 64   (total 34496 floats = 137984 B)

    {
        const float4* s = (const float4*)seqw1T;
        float4* d = (float4*)smem;
        for (int i = j; i < 8512; i += 64) d[i] = s[i];
    }
    tl[j] = times[b * Tn + j];       tl[j + 64] = times[b * Tn + 64 + j];
    ml[j] = mask[b * Tn + j];        ml[j + 64] = mask[b * Tn + 64 + j];

    float w0c[2][32], w0tc[2], b0c[2], b1c[2], b2c[2], ftsc[2], ftsh[2];
    #pragma unroll
    for (int l = 0; l < 2; l++) {
        #pragma unroll
        for (int kk = 0; kk < 32; kk++)
            w0c[l][kk] = fW0[(l * 65 + 32 * l + kk) * 64 + j];
        w0tc[l] = fW0[(l * 65 + 64) * 64 + j];
        b0c[l]  = fb0[l * 64 + j];
        b1c[l]  = fb1[l * 64 + j];
        const int act = 32 * (1 - l);
        b2c[l]  = fb2[l * 128 + act + (j & 31) + 64 * (j >> 5)];
        ftsc[l] = ftw[l * 128 + j];
        ftsh[l] = ftw[l * 128 + 64 + j];
    }
    const float wij = Wi[j];
    const float bi0 = bi[0];
    float wih0[4], gcr[4];
    #pragma unroll
    for (int r = 0; r < 4; r++) {
        wih0[r] = W_ih[(r * 64 + j) * 65];
        gcr[r]  = gc[b * 256 + r * 64 + j];
    }
    const float idn = invd[0];

    float h = 0.f, c = 0.f, nllacc = 0.f;
    for (int t = 0; t < Tn; t++) {
        const float tb = tl[t];
        float tscv[2], tshv[2];
        #pragma unroll
        for (int l = 0; l < 2; l++) {
            tscv[l] = tanhf_(tb * ftsc[l]);
            tshv[l] = tanhf_(tb * ftsh[l]);
        }
        h_carry[(b * Tn + t) * 64 + j] = h;      // fire-and-forget
        float x = h;
        xl[j] = x;
        #pragma unroll
        for (int l = 0; l < 2; l++) {
            const int kb  = 32 * l;
            const int act = 32 * (1 - l);
            // ---- mv1: batched 8 act loads, register weights ----
            {
                float4 xv[8];
                const float4* xv4 = (const float4*)(xl + kb);
                #pragma unroll
                for (int k4 = 0; k4 < 8; k4++) xv[k4] = xv4[k4];
                float p0 = b0c[l] + tb * w0tc[l], p1 = 0.f, p2 = 0.f, p3 = 0.f;
                #pragma unroll
                for (int k4 = 0; k4 < 8; k4++) {
                    p0 += xv[k4].x * w0c[l][4 * k4 + 0];
                    p1 += xv[k4].y * w0c[l][4 * k4 + 1];
                    p2 += xv[k4].z * w0c[l][4 * k4 + 2];
                    p3 += xv[k4].w * w0c[l][4 * k4 + 3];
                }
                al[j] = tanhf_((p0 + p1) + (p2 + p3));
            }
            // ---- mv2: batched 16 act + 16 weight loads, then FMAs ----
            {
                float4 av[16], wv[16];
                const float4* av4 = (const float4*)al;
                const float*  wp  = w1l + (l * 64 + j) * 68;
                #pragma unroll
                for (int k4 = 0; k4 < 16; k4++) {
                    wv[k4] = *(const float4*)(wp + 4 * k4);
                    av[k4] = av4[k4];
                }
                float p0 = b1c[l], p1 = 0.f, p2 = 0.f, p3 = 0.f;
                #pragma unroll
                for (int k4 = 0; k4 < 16; k4++) {
                    p0 += av[k4].x * wv[k4].x;
                    p1 += av[k4].y * wv[k4].y;
                    p2 += av[k4].z * wv[k4].z;
                    p3 += av[k4].w * wv[k4].w;
                }
                al[j] = tanhf_((p0 + p1) + (p2 + p3));
            }
            // ---- mv3: batched 16 act + 16 weight loads ----
            {
                float4 av[16], wv[16];
                const float4* av4 = (const float4*)al;
                const float*  wp  = w2l + (l * 64 + j) * 68;
                #pragma unroll
                for (int k4 = 0; k4 < 16; k4++) {
                    wv[k4] = *(const float4*)(wp + 4 * k4);
                    av[k4] = av4[k4];
                }
                float p0 = b2c[l], p1 = 0.f, p2 = 0.f, p3 = 0.f;
                #pragma unroll
                for (int k4 = 0; k4 < 16; k4++) {
                    p0 += av[k4].x * wv[k4].x;
                    p1 += av[k4].y * wv[k4].y;
                    p2 += av[k4].z * wv[k4].z;
                    p3 += av[k4].w * wv[k4].w;
                }
                ssl[j] = (p0 + p1) + (p2 + p3);
            }
            // coupling
            const int idx = (j - act) & 31;
            const float scl = ssl[idx];
            const float shf = ssl[idx + 32];
            const float xa  = x * __expf(scl * tscv[l]) + shf * tshv[l];
            const bool active = (l == 0) ? (j >= 32) : (j < 32);
            x = active ? xa : x;
            xl[j] = x;
        }
        out[1 + (b * Tn + t) * 64 + j] = x;      // h2, fire-and-forget
        // nll (off the recurrence path)
        float v = x * wij;
        #pragma unroll
        for (int off = 32; off >= 1; off >>= 1) v += __shfl_xor(v, off, 64);
        nllacc += -__logf(softplusf_(v + bi0)) * ml[t];
        // ---- LSTM: batched act loads + 4 chunks of 16 weight loads ----
        float g0 = gcr[0] + tb * wih0[0];
        float g1 = gcr[1] + tb * wih0[1];
        float g2 = gcr[2] + tb * wih0[2];
        float g3 = gcr[3] + tb * wih0[3];
        {
            float4 hv[16];
            const float4* hv4 = (const float4*)xl;
            #pragma unroll
            for (int k4 = 0; k4 < 16; k4++) hv[k4] = hv4[k4];
            const float* wr_base = whhl + j * 260;
            #pragma unroll
            for (int kc = 0; kc < 4; kc++) {
                float4 wv[16];
                #pragma unroll
                for (int k = 0; k < 16; k++)
                    wv[k] = *(const float4*)(wr_base + (kc * 16 + k) * 4);
                #pragma unroll
                for (int k = 0; k < 16; k++) {
                    const int kk = kc * 16 + k;
                    const float hk = ((const float*)hv)[kk];
                    g0 += hk * wv[k].x;
                    g1 += hk * wv[k].y;
                    g2 += hk * wv[k].z;
                    g3 += hk * wv[k].w;
                }
            }
        }
        c = sigmoidf_(g1) * c + sigmoidf_(g0) * tanhf_(g2);
        h = sigmoidf_(g3) * tanhf_(c);
    }
    if (j == 0) atomicAdd(out, nllacc * idn);
}

// ---------------------------------------------------------------------------
// Parallel kernel, MFMA bf16 (round-6 math), occupancy raised to 3 blocks/CU
// (cap ~170 VGPR; demand estimated ~140-160 -> no spill expected).
extern "C" __global__ __launch_bounds__(256, 3)
void par_kernel(const float* __restrict__ times, const float* __restrict__ mask,
                const float* __restrict__ u, const float* __restrict__ bi,
                const float* __restrict__ invd, const float* __restrict__ parv,
                const unsigned short* __restrict__ parwb,
                const float* __restrict__ h_carry, float* __restrict__ pp)
{
    __shared__ __align__(16) unsigned short sact[128 * 72];
    __shared__ __align__(16) unsigned short sxk1[128 * 40];
    __shared__ __align__(16) unsigned short sx0b[4 * 40];
    __shared__ float pr[4];

    const int tid = threadIdx.x, lane = tid & 63, w = tid >> 6;
    const int quad = lane >> 4, l15 = lane & 15;

    const int q = blockIdx.x * 4 + w;
    const int t = q >> 8, b = q & 255;
    const float tb = times[b * Tn + t];
    const float* hrow = h_carry + (b * Tn + t) * 64;
    if (lane < 32) sx0b[w * 40 + lane] = f2b(hrow[lane]);

    float tsv[2], sclf[2];
    {
        const float base = tb * (1.0f / 30.0f) * invd[0] * mask[b * Tn + t];
        #pragma unroll
        for (int nt = 0; nt < 2; nt++) {
            int mc = nt * 16 + l15;
            bool val = (mc < 30);
            tsv[nt]  = val ? u[t * MCn + mc] * tb : 0.f;
            sclf[nt] = val ? base : 0.f;
        }
    }
    f32x4 xr[2][4];
    #pragma unroll
    for (int mt = 0; mt < 4; mt++) {
        f32x4 v = *(const f32x4*)(hrow + mt * 16 + quad * 4);
        xr[0][mt] = v; xr[1][mt] = v;
    }
    const int srow = w * 32;

    #pragma unroll
    for (int l = 0; l < 2; l++) {
        const unsigned short* wA1 = parwb + l * 2560;
        const unsigned short* wA2 = parwb + 5120 + l * 4608;
        const unsigned short* wA3 = parwb + 14336 + l * 4608;
        // ---- mv1: K=32 ----
        f32x4 c1[4][2];
        if (l == 0) {
            bf16x8 bb = *(const bf16x8*)(sx0b + w * 40 + quad * 8);
            #pragma unroll
            for (int mt = 0; mt < 4; mt++) {
                bf16x8 af = *(const bf16x8*)(wA1 + (mt * 16 + l15) * 40 + quad * 8);
                f32x4 z = {0.f, 0.f, 0.f, 0.f};
                c1[mt][0] = __builtin_amdgcn_mfma_f32_16x16x32_bf16(af, bb, z, 0, 0, 0);
                c1[mt][1] = c1[mt][0];
            }
        } else {
            bf16x8 bf[2];
            #pragma unroll
            for (int nt = 0; nt < 2; nt++)
                bf[nt] = *(const bf16x8*)(sxk1 + (srow + nt * 16 + l15) * 40 + quad * 8);
            #pragma unroll
            for (int mt = 0; mt < 4; mt++) {
                bf16x8 af = *(const bf16x8*)(wA1 + (mt * 16 + l15) * 40 + quad * 8);
                #pragma unroll
                for (int nt = 0; nt < 2; nt++) {
                    f32x4 z = {0.f, 0.f, 0.f, 0.f};
                    c1[mt][nt] = __builtin_amdgcn_mfma_f32_16x16x32_bf16(af, bf[nt], z, 0, 0, 0);
                }
            }
        }
        #pragma unroll
        for (int mt = 0; mt < 4; mt++) {
            f32x4 b0r = *(const f32x4*)(parv + 0   + l * 64 + mt * 16 + quad * 4);
            f32x4 w0r = *(const f32x4*)(parv + 128 + l * 64 + mt * 16 + quad * 4);
            #pragma unroll
            for (int nt = 0; nt < 2; nt++) {
                float v0 = tanhf_(c1[mt][nt][0] + b0r[0] + tsv[nt] * w0r[0]);
                float v1 = tanhf_(c1[mt][nt][1] + b0r[1] + tsv[nt] * w0r[1]);
                float v2 = tanhf_(c1[mt][nt][2] + b0r[2] + tsv[nt] * w0r[2]);
                float v3 = tanhf_(c1[mt][nt][3] + b0r[3] + tsv[nt] * w0r[3]);
                uint2 pk; pk.x = pk2(v0, v1); pk.y = pk2(v2, v3);
                *(uint2*)(sact + (srow + nt * 16 + l15) * 72 + mt * 16 + quad * 4) = pk;
            }
        }
        // ---- mv2: K=64 ----
        f32x4 cc[4][2];
        #pragma unroll
        for (int mt = 0; mt < 4; mt++)
            #pragma unroll
            for (int nt = 0; nt < 2; nt++) cc[mt][nt] = (f32x4){0.f, 0.f, 0.f, 0.f};
        #pragma unroll
        for (int kt = 0; kt < 2; kt++) {
            bf16x8 bf[2];
            #pragma unroll
            for (int nt = 0; nt < 2; nt++)
                bf[nt] = *(const bf16x8*)(sact + (srow + nt * 16 + l15) * 72 + kt * 32 + quad * 8);
            #pragma unroll
            for (int mt = 0; mt < 4; mt++) {
                bf16x8 af = *(const bf16x8*)(wA2 + (mt * 16 + l15) * 72 + kt * 32 + quad * 8);
                #pragma unroll
                for (int nt = 0; nt < 2; nt++)
                    cc[mt][nt] = __builtin_amdgcn_mfma_f32_16x16x32_bf16(af, bf[nt], cc[mt][nt], 0, 0, 0);
            }
        }
        #pragma unroll
        for (int mt = 0; mt < 4; mt++) {
            f32x4 b1r = *(const f32x4*)(parv + 256 + l * 64 + mt * 16 + quad * 4);
            #pragma unroll
            for (int nt = 0; nt < 2; nt++) {
                float v0 = tanhf_(cc[mt][nt][0] + b1r[0]);
                float v1 = tanhf_(cc[mt][nt][1] + b1r[1]);
                float v2 = tanhf_(cc[mt][nt][2] + b1r[2]);
                float v3 = tanhf_(cc[mt][nt][3] + b1r[3]);
                uint2 pk; pk.x = pk2(v0, v1); pk.y = pk2(v2, v3);
                *(uint2*)(sact + (srow + nt * 16 + l15) * 72 + mt * 16 + quad * 4) = pk;
            }
        }
        // ---- mv3: K=64 ----
        f32x4 ssf[4][2];
        #pragma unroll
        for (int mt = 0; mt < 4; mt++)
            #pragma unroll
            for (int nt = 0; nt < 2; nt++) ssf[mt][nt] = (f32x4){0.f, 0.f, 0.f, 0.f};
        #pragma unroll
        for (int kt = 0; kt < 2; kt++) {
            bf16x8 bf[2];
            #pragma unroll
            for (int nt = 0; nt < 2; nt++)
                bf[nt] = *(const bf16x8*)(sact + (srow + nt * 16 + l15) * 72 + kt * 32 + quad * 8);
            #pragma unroll
            for (int mt = 0; mt < 4; mt++) {
                bf16x8 af = *(const bf16x8*)(wA3 + (mt * 16 + l15) * 72 + kt * 32 + quad * 8);
                #pragma unroll
                for (int nt = 0; nt < 2; nt++)
                    ssf[mt][nt] = __builtin_amdgcn_mfma_f32_16x16x32_bf16(af, bf[nt], ssf[mt][nt], 0, 0, 0);
            }
        }
        // coupling in registers
        #pragma unroll
        for (int mt2 = 0; mt2 < 2; mt2++) {
            f32x4 b2s = *(const f32x4*)(parv + 384 + l * 64 +      mt2 * 16 + quad * 4);
            f32x4 b2h = *(const f32x4*)(parv + 384 + l * 64 + 32 + mt2 * 16 + quad * 4);
            f32x4 fa  = *(const f32x4*)(parv + 512 + l * 32 + mt2 * 16 + quad * 4);
            f32x4 fb  = *(const f32x4*)(parv + 576 + l * 32 + mt2 * 16 + quad * 4);
            const int xm = (l == 0) ? (mt2 + 2) : mt2;
            #pragma unroll
            for (int nt = 0; nt < 2; nt++) {
                #pragma unroll
                for (int r = 0; r < 4; r++) {
                    float sc  = ssf[mt2][nt][r] + b2s[r];
                    float sh  = ssf[mt2 + 2][nt][r] + b2h[r];
                    float tsc = tanhf_(tsv[nt] * fa[r]);
                    float tsh = tanhf_(tsv[nt] * fb[r]);
                    float xv  = xr[nt][xm][r];
                    xr[nt][xm][r] = xv * __expf(sc * tsc) + sh * tsh;
                }
                if (l == 0) {
                    uint2 pk;
                    pk.x = pk2(xr[nt][xm][0], xr[nt][xm][1]);
                    pk.y = pk2(xr[nt][xm][2], xr[nt][xm][3]);
                    *(uint2*)(sxk1 + (srow + nt * 16 + l15) * 40 + mt2 * 16 + quad * 4) = pk;
                }
            }
        }
    }
    // ---- intensity + per-block loss partial ----
    float contrib = 0.f;
    const float bi0 = bi[0];
    #pragma unroll
    for (int nt = 0; nt < 2; nt++) {
        float d0 = 0.f, d1 = 0.f;
        #pragma unroll
        for (int mt = 0; mt < 4; mt++) {
            f32x4 wi4 = *(const f32x4*)(parv + 640 + mt * 16 + quad * 4);
            d0 += xr[nt][mt][0] * wi4[0] + xr[nt][mt][2] * wi4[2];
            d1 += xr[nt][mt][1] * wi4[1] + xr[nt][mt][3] * wi4[3];
        }
        float d = d0 + d1;
        d += __shfl_xor(d, 16, 64);
        d += __shfl_xor(d, 32, 64);
        contrib += softplusf_(d + bi0) * sclf[nt];
    }
    if (quad != 0) contrib = 0.f;
    #pragma unroll
    for (int off = 1; off <= 8; off <<= 1) contrib += __shfl_xor(contrib, off, 64);
    if (l15 == 0 && quad == 0) pr[w] = contrib;
    __syncthreads();
    if (tid == 0) pp[blockIdx.x] = pr[0] + pr[1] + pr[2] + pr[3];
}

// ---------------------------------------------------------------------------
extern "C" __global__ __launch_bounds__(256)
void fin_kernel(const float* __restrict__ pp, float* __restrict__ out)
{
    __shared__ float r4[4];
    const int tid = threadIdx.x;
    float s = 0.f;
    for (int i = tid; i < (Bn * Tn) / 4; i += 256) s += pp[i];
    #pragma unroll
    for (int off = 32; off >= 1; off >>= 1) s += __shfl_xor(s, off, 64);
    if ((tid & 63) == 0) r4[tid >> 6] = s;
    __syncthreads();
    if (tid == 0) atomicAdd(out, r4[0] + r4[1] + r4[2] + r4[3]);
}

// ---------------------------------------------------------------------------
extern "C" void kernel_launch(void* const* d_in, const int* in_sizes, int n_in,
                              void* d_out, int out_size, void* d_ws, size_t ws_size,
                              hipStream_t stream)
{
    const float* times = (const float*)d_in[0];
    const int*   marks = (const int*)  d_in[1];
    const float* mask  = (const float*)d_in[2];
    const float* u     = (const float*)d_in[3];
    const float* emb   = (const float*)d_in[4];
    const float* fW0   = (const float*)d_in[5];
    const float* fb0   = (const float*)d_in[6];
    const float* fW1   = (const float*)d_in[7];
    const float* fb1   = (const float*)d_in[8];
    const float* fW2   = (const float*)d_in[9];
    const float* fb2   = (const float*)d_in[10];
    const float* ftw   = (const float*)d_in[11];
    const float* Wi    = (const float*)d_in[12];
    const float* bi    = (const float*)d_in[13];
    const float* W_ih  = (const float*)d_in[14];
    const float* W_hh  = (const float*)d_in[15];
    const float* b_ih  = (const float*)d_in[16];
    const float* b_hh  = (const float*)d_in[17];
    float* out = (float*)d_out;

    float* wsp     = (float*)d_ws;
    float* h_carry = wsp;                   // 2,097,152
    float* gc      = h_carry + 2097152;     // 65,536
    float* invd    = gc + 65536;            // 4
    float* seqw1T  = invd + 4;              // 8,704  (w1l/w2l/whhl contiguous)
    float* seqw2T  = seqw1T + 8704;         // 8,704
    float* whh260  = seqw2T + 8704;         // 16,640
    float* parv    = whh260 + 16640;        // 768
    unsigned short* parwb = (unsigned short*)(parv + 768);   // 23,552 ushorts
    float* pp      = (float*)(parwb + 23552);                // 8,192

    hipMemsetAsync(d_out, 0, sizeof(float), stream);

    const int SEQ_SMEM = 34496 * 4;   // 137,984 B
    hipFuncSetAttribute((const void*)seq_kernel,
                        hipFuncAttributeMaxDynamicSharedMemorySize, SEQ_SMEM);

    prep_kernel<<<Bn + 8, 256, 0, stream>>>(marks, mask, emb, fW0, fW1, fW2,
                                            fb0, fb1, fb2, ftw, Wi, W_ih, W_hh,
                                            b_ih, b_hh, gc, invd, parv, parwb,
                                            seqw1T, seqw2T, whh260);
    seq_kernel<<<Bn, 64, SEQ_SMEM, stream>>>(times, mask, fW0, fb0, fb1, fb2,
                                             ftw, Wi, bi, W_ih, gc, seqw1T,
                                             invd, h_carry, out);
    par_kernel<<<(Bn * Tn) / 4, 256, 0, stream>>>(
        times, mask, u, bi, invd, parv, parwb, h_carry, pp);
    fin_kernel<<<1, 256, 0, stream>>>(pp, out);
}